// Round 14
// baseline (246.156 us; speedup 1.0000x reference)
//
#include <hip/hip_runtime.h>

#define L_LAYERS 783
#define L_PAD    784           // = SEGF*GF
#define B_BATCH  8192
#define N_SITES  784
#define K_KRAUS  16

#define SEGF     14
#define GF       56
#define TCW      36            // floats per layer (rows 0,2,3 of C,D,B)
#define NCOL     (B_BATCH / 256)   // 32 batch columns

// ---------------------------------------------------------------------------
// Hermitian-reduced + trace-preserving formulation (see R11/R12 notes).
// State v = (s00, s11, u, w); per layer v' = R v, R = C + D*xx0 + B*xx1;
// CPTP => R[0]+R[1] = [1,1,0,0]; rows {0,2,3} stored, row1 implicit.
// Pad layers (l >= 783): R = I.
// build_T also zeroes the epilogue counters (stream order protects seg).
// ---------------------------------------------------------------------------
__global__ void __launch_bounds__(256)
build_T(const float* __restrict__ kr, const float* __restrict__ ki,
        float* __restrict__ Tc, int* __restrict__ cnt) {
    __shared__ float lr[K_KRAUS * 16];
    __shared__ float li[K_KRAUS * 16];
    __shared__ float gr[32], gi[32];
    int l = blockIdx.x;
    int t = threadIdx.x;
    float* o = Tc + (size_t)l * TCW;

    if (l == 0 && t < NCOL) cnt[t] = 0;         // reset epilogue counters

    if (l >= L_LAYERS) {                        // identity pad layer
        if (t < 12) {
            int r3 = t >> 2, col = t & 3;
            int row = (r3 == 0) ? 0 : r3 + 1;   // 0,2,3
            o[t]      = (col == row) ? 1.f : 0.f;
            o[12 + t] = 0.f;
            o[24 + t] = 0.f;
        }
        return;
    }

    lr[t] = kr[(size_t)l * 256 + t];
    li[t] = ki[(size_t)l * 256 + t];
    __syncthreads();

    if (t < 128) {
        int e = t >> 2, chunk = t & 3;          // e in 0..31
        int ci = e >> 4;                        // 0,1
        int c = 0, d = ci;                      // (0,0),(0,1)
        int m = (e >> 2) & 3, q = e & 3;
        int i1 = m >> 1, j1 = m & 1, i2 = q >> 1, j2 = q & 1;
        int off1 = c * 4 + 2 * i1 + i2;
        int off2 = d * 4 + 2 * j1 + j2;
        float ar = 0.f, ai = 0.f;
        #pragma unroll
        for (int kk = 0; kk < 4; ++kk) {
            int kbase = (chunk * 4 + kk) * 16;
            #pragma unroll
            for (int a = 0; a < 2; ++a) {
                int x1 = kbase + a * 8 + off1;
                int x2 = kbase + a * 8 + off2;
                float k1r = lr[x1], k1i = li[x1];
                float k2r = lr[x2], k2i = li[x2];
                ar += k1r * k2r + k1i * k2i;    // K1 * conj(K2)
                ai += k1i * k2r - k1r * k2i;
            }
        }
        ar += __shfl_xor(ar, 1); ar += __shfl_xor(ar, 2);
        ai += __shfl_xor(ai, 1); ai += __shfl_xor(ai, 2);
        if (chunk == 0) { gr[e] = ar; gi[e] = ai; }
    }
    __syncthreads();

    if (t < 12) {
        int r3 = t >> 2, col = t & 3;
        int row = (r3 == 0) ? 0 : r3 + 1;       // 0,2,3
        int ci = (row == 0) ? 0 : 1;
        int base = ci * 16;
        float Ur[4], Ui[4];
        #pragma unroll
        for (int q = 0; q < 4; ++q) {
            if (col == 0)      { Ur[q] = gr[base + q];      Ui[q] = gi[base + q]; }
            else if (col == 1) { Ur[q] = gr[base + 12 + q]; Ui[q] = gi[base + 12 + q]; }
            else {
                float t1r = gr[base + 4 + q], t1i = gi[base + 4 + q];
                float t2r = gr[base + 8 + q], t2i = gi[base + 8 + q];
                if (col == 2) { Ur[q] = t1r + t2r;    Ui[q] = t1i + t2i; }
                else          { Ur[q] = -(t1i - t2i); Ui[q] = t1r - t2r; }   // i*(T1-T2)
            }
        }
        float A, Bc, Cc;
        if (row == 3) { A = Ui[0]; Bc = Ui[1] + Ui[2]; Cc = Ui[3]; }
        else          { A = Ur[0]; Bc = Ur[1] + Ur[2]; Cc = Ur[3]; }
        o[t]      = Cc;
        o[12 + t] = A - Cc;
        o[24 + t] = Bc;
    }
}

// ---------------------------------------------------------------------------
// Kernel 2: per (batch-column, segment) product of SEGF transfer matrices,
// with FUSED combine epilogue: the 56th block to finish a column chains all
// 56 segment matrices against the initial state and writes out[] directly.
// R12 body: wide staging (dwordx4 + b128), scalar-path Tc, rows {0,2,3}.
// ---------------------------------------------------------------------------
__global__ void __launch_bounds__(256, 4)
seg_fused(const float* __restrict__ X, const float* __restrict__ Tc,
          float* __restrict__ P, int* __restrict__ cnt,
          float* __restrict__ out) {
    __shared__ float4 xxs4[256 * 7];            // 28672 B; [row*7 + pair]
    __shared__ int isLast;
    int t  = threadIdx.x;
    int s  = blockIdx.y;
    int ls = s * SEGF;
    int b0 = blockIdx.x * 256;
    const float* tl0 = Tc + (size_t)ls * TCW;   // wave-uniform -> s_load
    const float2* Xp = (const float2*)X;

    // stage: pair p covers sites (ls+1+2p, ls+2+2p); only s=55,p=6 would
    // touch site 784 -> clamp start to 782, take .zw for real site.
    #pragma unroll
    for (int e = 0; e < 7; ++e) {
        int idx  = t + e * 256;                 // 0..1791
        int row  = idx / 7;
        int p    = idx - row * 7;
        int s0   = ls + 1 + 2 * p;
        bool cl  = (s0 > N_SITES - 2);
        int  s0c = cl ? (N_SITES - 2) : s0;
        float4 f = *(const float4*)(Xp + (size_t)(b0 + row) * N_SITES + s0c);
        float ax = cl ? f.z : f.x;
        float ay = cl ? f.w : f.y;
        float inva = __builtin_amdgcn_rcpf(fmaf(ax, ax, ay * ay));
        float invb = __builtin_amdgcn_rcpf(fmaf(f.z, f.z, f.w * f.w));
        xxs4[row * 7 + p] = make_float4(ax * ax * inva, ax * ay * inva,
                                        f.z * f.z * invb, f.z * f.w * invb);
    }
    __syncthreads();

    float pA[12], pB[12];
    #pragma unroll
    for (int i = 0; i < 12; ++i) pA[i] = 0.f;
    pA[0] = 1.f; pA[6] = 1.f; pA[11] = 1.f;     // identity rows {0,2,3}

#define STEPX(SRC, DST, I, XX0, XX1)                                            \
    {                                                                           \
        const float* tl = tl0 + (I) * TCW;      /* uniform -> s_load */         \
        float R[12];                                                            \
        _Pragma("unroll")                                                       \
        for (int e = 0; e < 12; ++e)                                            \
            R[e] = fmaf(tl[24 + e], (XX1), fmaf(tl[12 + e], (XX0), tl[e]));     \
        _Pragma("unroll")                                                       \
        for (int r = 0; r < 3; ++r) {                                           \
            float Rd = R[r * 4 + 0] - R[r * 4 + 1];                             \
            float R1 = R[r * 4 + 1];                                            \
            _Pragma("unroll")                                                   \
            for (int cc = 0; cc < 4; ++cc) {                                    \
                float base = (cc < 2) ? R1 : 0.f;                               \
                DST[r * 4 + cc] =                                               \
                    fmaf(Rd, SRC[cc],                                           \
                    fmaf(R[r * 4 + 2], SRC[4 + cc],                             \
                    fmaf(R[r * 4 + 3], SRC[8 + cc], base)));                    \
            }                                                                   \
        }                                                                       \
    }

    #pragma unroll
    for (int p = 0; p < 7; ++p) {               // 2 layers per LDS read
        float4 xp4 = xxs4[t * 7 + p];
        STEPX(pA, pB, 2 * p,     xp4.x, xp4.y);
        STEPX(pB, pA, 2 * p + 1, xp4.z, xp4.w);
    }
#undef STEPX

    int b = b0 + t;
    float4* P4 = (float4*)P;
    #pragma unroll
    for (int k = 0; k < 3; ++k)
        P4[((size_t)(s * 3 + k)) * B_BATCH + b] =
            make_float4(pA[4 * k], pA[4 * k + 1], pA[4 * k + 2], pA[4 * k + 3]);

    // ---- fused combine epilogue (last block of this batch-column) ----
    __threadfence();                            // my P stores device-visible
    __syncthreads();                            // all threads' stores fenced
    if (t == 0) {
        int old = __hip_atomic_fetch_add(&cnt[blockIdx.x], 1,
                                         __ATOMIC_ACQ_REL,
                                         __HIP_MEMORY_SCOPE_AGENT);
        isLast = (old == GF - 1) ? 1 : 0;
    }
    __syncthreads();
    if (!isLast) return;
    __threadfence();                            // acquire: see others' P

    float2 xv = Xp[(size_t)b * N_SITES];        // site 0
    float inv = __builtin_amdgcn_rcpf(fmaf(xv.x, xv.x, xv.y * xv.y));
    float v0 = xv.x * xv.x * inv;               // s00
    float v1 = xv.y * xv.y * inv;               // s11
    float v2 = xv.x * xv.y * inv;               // u
    float v3 = 0.f;                             // w
    const float4* P4c = (const float4*)P;
    #pragma unroll 4
    for (int s2 = 0; s2 < GF; ++s2) {
        float m[12];
        #pragma unroll
        for (int k = 0; k < 3; ++k) {
            float4 mv = P4c[((size_t)(s2 * 3 + k)) * B_BATCH + b];
            m[4 * k + 0] = mv.x; m[4 * k + 1] = mv.y;
            m[4 * k + 2] = mv.z; m[4 * k + 3] = mv.w;
        }
        float n0 = fmaf(m[0], v0, fmaf(m[1], v1, fmaf(m[2],  v2, m[3]  * v3)));
        float n2 = fmaf(m[4], v0, fmaf(m[5], v1, fmaf(m[6],  v2, m[7]  * v3)));
        float n3 = fmaf(m[8], v0, fmaf(m[9], v1, fmaf(m[10], v2, m[11] * v3)));
        float n1 = (v0 + v1) - n0;              // trace conservation
        v0 = n0; v1 = n1; v2 = n2; v3 = n3;
    }
    out[b] = v0;
}

// ---------------------------------------------------------------------------
extern "C" void kernel_launch(void* const* d_in, const int* in_sizes, int n_in,
                              void* d_out, int out_size, void* d_ws, size_t ws_size,
                              hipStream_t stream) {
    const float* X  = (const float*)d_in[0];
    const float* kr = (const float*)d_in[1];
    const float* ki = (const float*)d_in[2];
    float* out = (float*)d_out;

    const size_t Tb = ((size_t)L_PAD * TCW * sizeof(float) + 255) & ~(size_t)255;
    const size_t Pb = (size_t)GF * 3 * B_BATCH * sizeof(float4);   // 22,020,096
    float* Tc  = (float*)d_ws;
    float* P   = (float*)((char*)d_ws + Tb);
    int*   cnt = (int*)((char*)d_ws + Tb + Pb);

    build_T<<<L_PAD, 256, 0, stream>>>(kr, ki, Tc, cnt);

    dim3 gs(NCOL, GF);
    seg_fused<<<gs, 256, 0, stream>>>(X, Tc, P, cnt, out);
}

// Round 15
// 114.321 us; speedup vs baseline: 2.1532x; 2.1532x over previous
//
#include <hip/hip_runtime.h>

#define L_LAYERS 783
#define L_PAD    784           // = SEGF*GF
#define B_BATCH  8192
#define N_SITES  784
#define K_KRAUS  16

#define SEGF     14
#define HSEG     7             // half-segment per thread
#define GF       56
#define TCW      36            // floats per layer (rows 0,2,3 of C,D,B)
#define BPB      128           // batches per block (2 threads/batch)

// ---------------------------------------------------------------------------
// Hermitian-reduced + trace-preserving formulation (R11/R12).
// State v = (s00, s11, u, w); per layer v' = R v, R = C + D*xx0 + B*xx1;
// CPTP => R[0]+R[1] = [1,1,0,0]; rows {0,2,3} stored, row1 implicit.
// Pad layers (l >= 783): R = I.
// ---------------------------------------------------------------------------
__global__ void __launch_bounds__(256)
build_T(const float* __restrict__ kr, const float* __restrict__ ki,
        float* __restrict__ Tc) {
    __shared__ float lr[K_KRAUS * 16];
    __shared__ float li[K_KRAUS * 16];
    __shared__ float gr[32], gi[32];
    int l = blockIdx.x;
    int t = threadIdx.x;
    float* o = Tc + (size_t)l * TCW;

    if (l >= L_LAYERS) {                        // identity pad layer
        if (t < 12) {
            int r3 = t >> 2, col = t & 3;
            int row = (r3 == 0) ? 0 : r3 + 1;   // 0,2,3
            o[t]      = (col == row) ? 1.f : 0.f;
            o[12 + t] = 0.f;
            o[24 + t] = 0.f;
        }
        return;
    }

    lr[t] = kr[(size_t)l * 256 + t];
    li[t] = ki[(size_t)l * 256 + t];
    __syncthreads();

    if (t < 128) {
        int e = t >> 2, chunk = t & 3;          // e in 0..31
        int ci = e >> 4;                        // 0,1
        int c = 0, d = ci;                      // (0,0),(0,1)
        int m = (e >> 2) & 3, q = e & 3;
        int i1 = m >> 1, j1 = m & 1, i2 = q >> 1, j2 = q & 1;
        int off1 = c * 4 + 2 * i1 + i2;
        int off2 = d * 4 + 2 * j1 + j2;
        float ar = 0.f, ai = 0.f;
        #pragma unroll
        for (int kk = 0; kk < 4; ++kk) {
            int kbase = (chunk * 4 + kk) * 16;
            #pragma unroll
            for (int a = 0; a < 2; ++a) {
                int x1 = kbase + a * 8 + off1;
                int x2 = kbase + a * 8 + off2;
                float k1r = lr[x1], k1i = li[x1];
                float k2r = lr[x2], k2i = li[x2];
                ar += k1r * k2r + k1i * k2i;    // K1 * conj(K2)
                ai += k1i * k2r - k1r * k2i;
            }
        }
        ar += __shfl_xor(ar, 1); ar += __shfl_xor(ar, 2);
        ai += __shfl_xor(ai, 1); ai += __shfl_xor(ai, 2);
        if (chunk == 0) { gr[e] = ar; gi[e] = ai; }
    }
    __syncthreads();

    if (t < 12) {
        int r3 = t >> 2, col = t & 3;
        int row = (r3 == 0) ? 0 : r3 + 1;       // 0,2,3
        int ci = (row == 0) ? 0 : 1;
        int base = ci * 16;
        float Ur[4], Ui[4];
        #pragma unroll
        for (int q = 0; q < 4; ++q) {
            if (col == 0)      { Ur[q] = gr[base + q];      Ui[q] = gi[base + q]; }
            else if (col == 1) { Ur[q] = gr[base + 12 + q]; Ui[q] = gi[base + 12 + q]; }
            else {
                float t1r = gr[base + 4 + q], t1i = gi[base + 4 + q];
                float t2r = gr[base + 8 + q], t2i = gi[base + 8 + q];
                if (col == 2) { Ur[q] = t1r + t2r;    Ui[q] = t1i + t2i; }
                else          { Ur[q] = -(t1i - t2i); Ui[q] = t1r - t2r; }   // i*(T1-T2)
            }
        }
        float A, Bc, Cc;
        if (row == 3) { A = Ui[0]; Bc = Ui[1] + Ui[2]; Cc = Ui[3]; }
        else          { A = Ur[0]; Bc = Ur[1] + Ur[2]; Cc = Ur[3]; }
        o[t]      = Cc;
        o[12 + t] = A - Cc;
        o[24 + t] = Bc;
    }
}

// ---------------------------------------------------------------------------
// Kernel 2: per (128-batch column, segment) product of SEGF transfer
// matrices, SPLIT across 2 threads/batch: t<128 computes layers 0..6 (QA),
// t>=128 layers 7..13 (QB); LDS exchange; A-thread merges Q = QB*QA and
// stores. LDS = 22.0 KB -> 7 blocks/CU = 28 waves/CU; grid 3584 = exactly
// 2 full rounds of half-size work (was 1.4 rounds of full-size).
// Tc via scalar s_load (half is wave-uniform). P SoA as 3x dwordx4.
// ---------------------------------------------------------------------------
__global__ void __launch_bounds__(256, 7)
seg_fused(const float* __restrict__ X, const float* __restrict__ Tc,
          float* __restrict__ P) {
    __shared__ float2 xxs[BPB * 15];            // stride-15 pad: 15360 B
    __shared__ float  qx[BPB][13];              // 6656 B exchange
    int t  = threadIdx.x;
    int s  = blockIdx.y;
    int ls = s * SEGF;
    int b0 = blockIdx.x * BPB;
    const float2* Xp = (const float2*)X;

    // coalesced transpose stage: 128 rows x 14 sites
    #pragma unroll
    for (int e = 0; e < 7; ++e) {
        int idx  = t + e * 256;                 // 0..1791
        int row  = idx / 14;
        int col  = idx - row * 14;
        int site = ls + 1 + col;
        site = site < (N_SITES - 1) ? site : (N_SITES - 1);   // pad clamp
        float2 xv = Xp[(size_t)(b0 + row) * N_SITES + site];
        float inv = __builtin_amdgcn_rcpf(fmaf(xv.x, xv.x, xv.y * xv.y));
        xxs[row * 15 + col] = make_float2(xv.x * xv.x * inv, xv.x * xv.y * inv);
    }
    __syncthreads();

    int half = t >> 7;                          // wave-uniform (waves 0,1 / 2,3)
    int bt   = t & (BPB - 1);
    const float* tlh = Tc + (size_t)(ls + half * HSEG) * TCW;   // s_load base

    float pA[12], pB[12];
    #pragma unroll
    for (int i = 0; i < 12; ++i) pA[i] = 0.f;
    pA[0] = 1.f; pA[6] = 1.f; pA[11] = 1.f;     // identity rows {0,2,3}

#define STEP(SRC, DST, I)                                                       \
    {                                                                           \
        const float* tl = tlh + (I) * TCW;      /* uniform -> s_load */         \
        float2 xx = xxs[bt * 15 + half * HSEG + (I)];                           \
        float R[12];                                                            \
        _Pragma("unroll")                                                       \
        for (int e = 0; e < 12; ++e)                                            \
            R[e] = fmaf(tl[24 + e], xx.y, fmaf(tl[12 + e], xx.x, tl[e]));       \
        _Pragma("unroll")                                                       \
        for (int r = 0; r < 3; ++r) {                                           \
            float Rd = R[r * 4 + 0] - R[r * 4 + 1];                             \
            float R1 = R[r * 4 + 1];                                            \
            _Pragma("unroll")                                                   \
            for (int cc = 0; cc < 4; ++cc) {                                    \
                float base = (cc < 2) ? R1 : 0.f;                               \
                DST[r * 4 + cc] =                                               \
                    fmaf(Rd, SRC[cc],                                           \
                    fmaf(R[r * 4 + 2], SRC[4 + cc],                             \
                    fmaf(R[r * 4 + 3], SRC[8 + cc], base)));                    \
            }                                                                   \
        }                                                                       \
    }

    // 7 layers (odd) -> result lands in pB
    STEP(pA, pB, 0); STEP(pB, pA, 1);
    STEP(pA, pB, 2); STEP(pB, pA, 3);
    STEP(pA, pB, 4); STEP(pB, pA, 5);
    STEP(pA, pB, 6);
#undef STEP

    if (half == 1) {                            // publish QB
        #pragma unroll
        for (int i = 0; i < 12; ++i) qx[bt][i] = pB[i];
    }
    __syncthreads();

    if (half == 0) {                            // merge Q = QB * QA, store
        float m[12];
        #pragma unroll
        for (int i = 0; i < 12; ++i) m[i] = qx[bt][i];
        float q[12];
        #pragma unroll
        for (int r = 0; r < 3; ++r) {
            float Rd = m[r * 4 + 0] - m[r * 4 + 1];
            float R1 = m[r * 4 + 1];
            #pragma unroll
            for (int cc = 0; cc < 4; ++cc) {
                float base = (cc < 2) ? R1 : 0.f;
                q[r * 4 + cc] =
                    fmaf(Rd, pB[cc],
                    fmaf(m[r * 4 + 2], pB[4 + cc],
                    fmaf(m[r * 4 + 3], pB[8 + cc], base)));
            }
        }
        int b = b0 + bt;
        float4* P4 = (float4*)P;
        #pragma unroll
        for (int k = 0; k < 3; ++k)
            P4[((size_t)(s * 3 + k)) * B_BATCH + b] =
                make_float4(q[4 * k], q[4 * k + 1], q[4 * k + 2], q[4 * k + 3]);
    }
}

// ---------------------------------------------------------------------------
// Kernel 3: two-level combine (8 groups x 7-chain, then 8-chain). R12 exact.
// ---------------------------------------------------------------------------
__global__ void __launch_bounds__(256)
combine56(const float* __restrict__ X, const float* __restrict__ P,
          float* __restrict__ out) {
    __shared__ float q[256][13];
    int t = threadIdx.x;
    int j = t >> 5, bl = t & 31;
    int b = blockIdx.x * 32 + bl;
    const float4* P4 = (const float4*)P;

    float qa[12], qb[12];
    #pragma unroll
    for (int i = 0; i < 12; ++i) qa[i] = 0.f;
    qa[0] = 1.f; qa[6] = 1.f; qa[11] = 1.f;

#define CSTEP(SRC, DST, K)                                                      \
    {                                                                           \
        float m[12];                                                            \
        _Pragma("unroll")                                                       \
        for (int k = 0; k < 3; ++k) {                                           \
            float4 mv = P4[((size_t)((j * 7 + (K)) * 3 + k)) * B_BATCH + b];    \
            m[4 * k + 0] = mv.x; m[4 * k + 1] = mv.y;                           \
            m[4 * k + 2] = mv.z; m[4 * k + 3] = mv.w;                           \
        }                                                                       \
        _Pragma("unroll")                                                       \
        for (int r = 0; r < 3; ++r) {                                           \
            float Rd = m[r * 4 + 0] - m[r * 4 + 1];                             \
            float R1 = m[r * 4 + 1];                                            \
            _Pragma("unroll")                                                   \
            for (int cc = 0; cc < 4; ++cc) {                                    \
                float base = (cc < 2) ? R1 : 0.f;                               \
                DST[r * 4 + cc] =                                               \
                    fmaf(Rd, SRC[cc],                                           \
                    fmaf(m[r * 4 + 2], SRC[4 + cc],                             \
                    fmaf(m[r * 4 + 3], SRC[8 + cc], base)));                    \
            }                                                                   \
        }                                                                       \
    }
    CSTEP(qa, qb, 0); CSTEP(qb, qa, 1);
    CSTEP(qa, qb, 2); CSTEP(qb, qa, 3);
    CSTEP(qa, qb, 4); CSTEP(qb, qa, 5);
    CSTEP(qa, qb, 6);                          // result in qb
#undef CSTEP

    #pragma unroll
    for (int i = 0; i < 12; ++i) q[t][i] = qb[i];
    __syncthreads();

    if (t < 32) {
        int b2 = blockIdx.x * 32 + t;
        const float2* Xp = (const float2*)X;
        float2 xv = Xp[(size_t)b2 * N_SITES];
        float inv = __builtin_amdgcn_rcpf(fmaf(xv.x, xv.x, xv.y * xv.y));
        float v0 = xv.x * xv.x * inv;          // s00
        float v1 = xv.y * xv.y * inv;          // s11
        float v2 = xv.x * xv.y * inv;          // u
        float v3 = 0.f;                        // w
        #pragma unroll
        for (int jj = 0; jj < 8; ++jj) {
            const float* qq = q[jj * 32 + t];
            float n0 = fmaf(qq[0], v0, fmaf(qq[1], v1, fmaf(qq[2],  v2, qq[3]  * v3)));
            float n2 = fmaf(qq[4], v0, fmaf(qq[5], v1, fmaf(qq[6],  v2, qq[7]  * v3)));
            float n3 = fmaf(qq[8], v0, fmaf(qq[9], v1, fmaf(qq[10], v2, qq[11] * v3)));
            float n1 = (v0 + v1) - n0;         // trace conservation
            v0 = n0; v1 = n1; v2 = n2; v3 = n3;
        }
        out[b2] = v0;
    }
}

// ---------------------------------------------------------------------------
extern "C" void kernel_launch(void* const* d_in, const int* in_sizes, int n_in,
                              void* d_out, int out_size, void* d_ws, size_t ws_size,
                              hipStream_t stream) {
    const float* X  = (const float*)d_in[0];
    const float* kr = (const float*)d_in[1];
    const float* ki = (const float*)d_in[2];
    float* out = (float*)d_out;

    float* Tc = (float*)d_ws;
    const size_t Tb = ((size_t)L_PAD * TCW * sizeof(float) + 255) & ~(size_t)255;
    float* P = (float*)((char*)d_ws + Tb);      // 56*3*8192*16 = 22.0 MB

    build_T<<<L_PAD, 256, 0, stream>>>(kr, ki, Tc);

    dim3 gs(B_BATCH / BPB, GF);
    seg_fused<<<gs, 256, 0, stream>>>(X, Tc, P);

    combine56<<<B_BATCH / 32, 256, 0, stream>>>(X, P, out);
}

// Round 16
// 50.914 us; speedup vs baseline: 4.8348x; 2.2454x over previous
//
#include <hip/hip_runtime.h>

#define L_LAYERS 783
#define L_PAD    784           // = SEGF*GF
#define B_BATCH  8192
#define N_SITES  784
#define K_KRAUS  16

#define SEGF     14
#define HSEG     7             // half-segment per thread
#define GF       56
#define TCW      36            // floats per layer (rows 0,2,3 of C,D,B)
#define BPB      128           // batches per block (2 threads/batch)

// ---------------------------------------------------------------------------
// Hermitian-reduced + trace-preserving formulation (R11/R12).
// State v = (s00, s11, u, w); per layer v' = R v, R = C + D*xx0 + B*xx1;
// CPTP => R[0]+R[1] = [1,1,0,0]; rows {0,2,3} stored, row1 implicit.
// Pad layers (l >= 783): R = I.
// ---------------------------------------------------------------------------
__global__ void __launch_bounds__(256)
build_T(const float* __restrict__ kr, const float* __restrict__ ki,
        float* __restrict__ Tc) {
    __shared__ float lr[K_KRAUS * 16];
    __shared__ float li[K_KRAUS * 16];
    __shared__ float gr[32], gi[32];
    int l = blockIdx.x;
    int t = threadIdx.x;
    float* o = Tc + (size_t)l * TCW;

    if (l >= L_LAYERS) {                        // identity pad layer
        if (t < 12) {
            int r3 = t >> 2, col = t & 3;
            int row = (r3 == 0) ? 0 : r3 + 1;   // 0,2,3
            o[t]      = (col == row) ? 1.f : 0.f;
            o[12 + t] = 0.f;
            o[24 + t] = 0.f;
        }
        return;
    }

    lr[t] = kr[(size_t)l * 256 + t];
    li[t] = ki[(size_t)l * 256 + t];
    __syncthreads();

    if (t < 128) {
        int e = t >> 2, chunk = t & 3;          // e in 0..31
        int ci = e >> 4;                        // 0,1
        int c = 0, d = ci;                      // (0,0),(0,1)
        int m = (e >> 2) & 3, q = e & 3;
        int i1 = m >> 1, j1 = m & 1, i2 = q >> 1, j2 = q & 1;
        int off1 = c * 4 + 2 * i1 + i2;
        int off2 = d * 4 + 2 * j1 + j2;
        float ar = 0.f, ai = 0.f;
        #pragma unroll
        for (int kk = 0; kk < 4; ++kk) {
            int kbase = (chunk * 4 + kk) * 16;
            #pragma unroll
            for (int a = 0; a < 2; ++a) {
                int x1 = kbase + a * 8 + off1;
                int x2 = kbase + a * 8 + off2;
                float k1r = lr[x1], k1i = li[x1];
                float k2r = lr[x2], k2i = li[x2];
                ar += k1r * k2r + k1i * k2i;    // K1 * conj(K2)
                ai += k1i * k2r - k1r * k2i;
            }
        }
        ar += __shfl_xor(ar, 1); ar += __shfl_xor(ar, 2);
        ai += __shfl_xor(ai, 1); ai += __shfl_xor(ai, 2);
        if (chunk == 0) { gr[e] = ar; gi[e] = ai; }
    }
    __syncthreads();

    if (t < 12) {
        int r3 = t >> 2, col = t & 3;
        int row = (r3 == 0) ? 0 : r3 + 1;       // 0,2,3
        int ci = (row == 0) ? 0 : 1;
        int base = ci * 16;
        float Ur[4], Ui[4];
        #pragma unroll
        for (int q = 0; q < 4; ++q) {
            if (col == 0)      { Ur[q] = gr[base + q];      Ui[q] = gi[base + q]; }
            else if (col == 1) { Ur[q] = gr[base + 12 + q]; Ui[q] = gi[base + 12 + q]; }
            else {
                float t1r = gr[base + 4 + q], t1i = gi[base + 4 + q];
                float t2r = gr[base + 8 + q], t2i = gi[base + 8 + q];
                if (col == 2) { Ur[q] = t1r + t2r;    Ui[q] = t1i + t2i; }
                else          { Ur[q] = -(t1i - t2i); Ui[q] = t1r - t2r; }   // i*(T1-T2)
            }
        }
        float A, Bc, Cc;
        if (row == 3) { A = Ui[0]; Bc = Ui[1] + Ui[2]; Cc = Ui[3]; }
        else          { A = Ur[0]; Bc = Ur[1] + Ur[2]; Cc = Ur[3]; }
        o[t]      = Cc;
        o[12 + t] = A - Cc;
        o[24 + t] = Bc;
    }
}

// ---------------------------------------------------------------------------
// Kernel 2: per (128-batch column, segment) product of SEGF transfer
// matrices, SPLIT across 2 threads/batch: t<128 computes layers 0..6 (QA),
// t>=128 layers 7..13 (QB); LDS exchange; A-thread merges Q = QB*QA.
// NO min-occupancy bound (R15's (256,7) forced 36 VGPR -> scratch spills,
// 297 MB of scratch writes). Natural VGPR ~52-60; LDS 22.0 KB -> 7 blk/CU.
// Tc via scalar s_load (half is wave-uniform). P SoA as 3x dwordx4.
// ---------------------------------------------------------------------------
__global__ void __launch_bounds__(256)
seg_fused(const float* __restrict__ X, const float* __restrict__ Tc,
          float* __restrict__ P) {
    __shared__ float2 xxs[BPB * 15];            // stride-15 pad: 15360 B
    __shared__ float  qx[BPB][13];              // 6656 B exchange
    int t  = threadIdx.x;
    int s  = blockIdx.y;
    int ls = s * SEGF;
    int b0 = blockIdx.x * BPB;
    const float2* Xp = (const float2*)X;

    // coalesced transpose stage: 128 rows x 14 sites
    #pragma unroll
    for (int e = 0; e < 7; ++e) {
        int idx  = t + e * 256;                 // 0..1791
        int row  = idx / 14;
        int col  = idx - row * 14;
        int site = ls + 1 + col;
        site = site < (N_SITES - 1) ? site : (N_SITES - 1);   // pad clamp
        float2 xv = Xp[(size_t)(b0 + row) * N_SITES + site];
        float inv = __builtin_amdgcn_rcpf(fmaf(xv.x, xv.x, xv.y * xv.y));
        xxs[row * 15 + col] = make_float2(xv.x * xv.x * inv, xv.x * xv.y * inv);
    }
    __syncthreads();

    int half = t >> 7;                          // wave-uniform (waves 0,1 / 2,3)
    int bt   = t & (BPB - 1);
    const float* tlh = Tc + (size_t)(ls + half * HSEG) * TCW;   // s_load base

    float pA[12], pB[12];
    #pragma unroll
    for (int i = 0; i < 12; ++i) pA[i] = 0.f;
    pA[0] = 1.f; pA[6] = 1.f; pA[11] = 1.f;     // identity rows {0,2,3}

#define STEP(SRC, DST, I)                                                       \
    {                                                                           \
        const float* tl = tlh + (I) * TCW;      /* uniform -> s_load */         \
        float2 xx = xxs[bt * 15 + half * HSEG + (I)];                           \
        float R[12];                                                            \
        _Pragma("unroll")                                                       \
        for (int e = 0; e < 12; ++e)                                            \
            R[e] = fmaf(tl[24 + e], xx.y, fmaf(tl[12 + e], xx.x, tl[e]));       \
        _Pragma("unroll")                                                       \
        for (int r = 0; r < 3; ++r) {                                           \
            float Rd = R[r * 4 + 0] - R[r * 4 + 1];                             \
            float R1 = R[r * 4 + 1];                                            \
            _Pragma("unroll")                                                   \
            for (int cc = 0; cc < 4; ++cc) {                                    \
                float base = (cc < 2) ? R1 : 0.f;                               \
                DST[r * 4 + cc] =                                               \
                    fmaf(Rd, SRC[cc],                                           \
                    fmaf(R[r * 4 + 2], SRC[4 + cc],                             \
                    fmaf(R[r * 4 + 3], SRC[8 + cc], base)));                    \
            }                                                                   \
        }                                                                       \
    }

    // 7 layers (odd) -> result lands in pB
    STEP(pA, pB, 0); STEP(pB, pA, 1);
    STEP(pA, pB, 2); STEP(pB, pA, 3);
    STEP(pA, pB, 4); STEP(pB, pA, 5);
    STEP(pA, pB, 6);
#undef STEP

    if (half == 1) {                            // publish QB
        #pragma unroll
        for (int i = 0; i < 12; ++i) qx[bt][i] = pB[i];
    }
    __syncthreads();

    if (half == 0) {                            // merge Q = QB * QA, store
        float m[12];
        #pragma unroll
        for (int i = 0; i < 12; ++i) m[i] = qx[bt][i];
        float q[12];
        #pragma unroll
        for (int r = 0; r < 3; ++r) {
            float Rd = m[r * 4 + 0] - m[r * 4 + 1];
            float R1 = m[r * 4 + 1];
            #pragma unroll
            for (int cc = 0; cc < 4; ++cc) {
                float base = (cc < 2) ? R1 : 0.f;
                q[r * 4 + cc] =
                    fmaf(Rd, pB[cc],
                    fmaf(m[r * 4 + 2], pB[4 + cc],
                    fmaf(m[r * 4 + 3], pB[8 + cc], base)));
            }
        }
        int b = b0 + bt;
        float4* P4 = (float4*)P;
        #pragma unroll
        for (int k = 0; k < 3; ++k)
            P4[((size_t)(s * 3 + k)) * B_BATCH + b] =
                make_float4(q[4 * k], q[4 * k + 1], q[4 * k + 2], q[4 * k + 3]);
    }
}

// ---------------------------------------------------------------------------
// Kernel 3: two-level combine (8 groups x 7-chain, then 8-chain). R12 exact.
// ---------------------------------------------------------------------------
__global__ void __launch_bounds__(256)
combine56(const float* __restrict__ X, const float* __restrict__ P,
          float* __restrict__ out) {
    __shared__ float q[256][13];
    int t = threadIdx.x;
    int j = t >> 5, bl = t & 31;
    int b = blockIdx.x * 32 + bl;
    const float4* P4 = (const float4*)P;

    float qa[12], qb[12];
    #pragma unroll
    for (int i = 0; i < 12; ++i) qa[i] = 0.f;
    qa[0] = 1.f; qa[6] = 1.f; qa[11] = 1.f;

#define CSTEP(SRC, DST, K)                                                      \
    {                                                                           \
        float m[12];                                                            \
        _Pragma("unroll")                                                       \
        for (int k = 0; k < 3; ++k) {                                           \
            float4 mv = P4[((size_t)((j * 7 + (K)) * 3 + k)) * B_BATCH + b];    \
            m[4 * k + 0] = mv.x; m[4 * k + 1] = mv.y;                           \
            m[4 * k + 2] = mv.z; m[4 * k + 3] = mv.w;                           \
        }                                                                       \
        _Pragma("unroll")                                                       \
        for (int r = 0; r < 3; ++r) {                                           \
            float Rd = m[r * 4 + 0] - m[r * 4 + 1];                             \
            float R1 = m[r * 4 + 1];                                            \
            _Pragma("unroll")                                                   \
            for (int cc = 0; cc < 4; ++cc) {                                    \
                float base = (cc < 2) ? R1 : 0.f;                               \
                DST[r * 4 + cc] =                                               \
                    fmaf(Rd, SRC[cc],                                           \
                    fmaf(m[r * 4 + 2], SRC[4 + cc],                             \
                    fmaf(m[r * 4 + 3], SRC[8 + cc], base)));                    \
            }                                                                   \
        }                                                                       \
    }
    CSTEP(qa, qb, 0); CSTEP(qb, qa, 1);
    CSTEP(qa, qb, 2); CSTEP(qb, qa, 3);
    CSTEP(qa, qb, 4); CSTEP(qb, qa, 5);
    CSTEP(qa, qb, 6);                          // result in qb
#undef CSTEP

    #pragma unroll
    for (int i = 0; i < 12; ++i) q[t][i] = qb[i];
    __syncthreads();

    if (t < 32) {
        int b2 = blockIdx.x * 32 + t;
        const float2* Xp = (const float2*)X;
        float2 xv = Xp[(size_t)b2 * N_SITES];
        float inv = __builtin_amdgcn_rcpf(fmaf(xv.x, xv.x, xv.y * xv.y));
        float v0 = xv.x * xv.x * inv;          // s00
        float v1 = xv.y * xv.y * inv;          // s11
        float v2 = xv.x * xv.y * inv;          // u
        float v3 = 0.f;                        // w
        #pragma unroll
        for (int jj = 0; jj < 8; ++jj) {
            const float* qq = q[jj * 32 + t];
            float n0 = fmaf(qq[0], v0, fmaf(qq[1], v1, fmaf(qq[2],  v2, qq[3]  * v3)));
            float n2 = fmaf(qq[4], v0, fmaf(qq[5], v1, fmaf(qq[6],  v2, qq[7]  * v3)));
            float n3 = fmaf(qq[8], v0, fmaf(qq[9], v1, fmaf(qq[10], v2, qq[11] * v3)));
            float n1 = (v0 + v1) - n0;         // trace conservation
            v0 = n0; v1 = n1; v2 = n2; v3 = n3;
        }
        out[b2] = v0;
    }
}

// ---------------------------------------------------------------------------
extern "C" void kernel_launch(void* const* d_in, const int* in_sizes, int n_in,
                              void* d_out, int out_size, void* d_ws, size_t ws_size,
                              hipStream_t stream) {
    const float* X  = (const float*)d_in[0];
    const float* kr = (const float*)d_in[1];
    const float* ki = (const float*)d_in[2];
    float* out = (float*)d_out;

    float* Tc = (float*)d_ws;
    const size_t Tb = ((size_t)L_PAD * TCW * sizeof(float) + 255) & ~(size_t)255;
    float* P = (float*)((char*)d_ws + Tb);      // 56*3*8192*16 = 22.0 MB

    build_T<<<L_PAD, 256, 0, stream>>>(kr, ki, Tc);

    dim3 gs(B_BATCH / BPB, GF);
    seg_fused<<<gs, 256, 0, stream>>>(X, Tc, P);

    combine56<<<B_BATCH / 32, 256, 0, stream>>>(X, P, out);
}

// Round 17
// 36.146 us; speedup vs baseline: 6.8100x; 1.4085x over previous
//
#include <hip/hip_runtime.h>

#define L_LAYERS 783
#define L_PAD    784           // = SEGF*GF
#define B_BATCH  8192
#define N_SITES  784
#define K_KRAUS  16

#define SEGF     14
#define GF       56
#define TCW      36            // floats per layer (rows 0,2,3 of C,D,B)
#define PW       12            // floats per P matrix (rows 0,2,3)

// ---------------------------------------------------------------------------
// Hermitian-reduced + trace-preserving formulation.
// State v = (s00, s11, u, w).  Per layer v' = R v with
//   R = C + D*xx0 + B*xx1, and CPTP gives R[0]+R[1] = [1,1,0,0]:
// only rows {0,2,3} stored (36 floats: C(12) | D(12) | B(12)); row 1 of any
// product is reconstructed as P[1][c] = [1,1,0,0][c] - P[0][c].
// Pad layers (l >= 783): R = I.
// ---------------------------------------------------------------------------
__global__ void __launch_bounds__(256)
build_T(const float* __restrict__ kr, const float* __restrict__ ki,
        float* __restrict__ Tc) {
    __shared__ float lr[K_KRAUS * 16];
    __shared__ float li[K_KRAUS * 16];
    __shared__ float gr[32], gi[32];
    int l = blockIdx.x;
    int t = threadIdx.x;
    float* o = Tc + (size_t)l * TCW;

    if (l >= L_LAYERS) {                        // identity pad layer
        if (t < 12) {
            int r3 = t >> 2, col = t & 3;
            int row = (r3 == 0) ? 0 : r3 + 1;   // 0,2,3
            o[t]      = (col == row) ? 1.f : 0.f;
            o[12 + t] = 0.f;
            o[24 + t] = 0.f;
        }
        return;
    }

    lr[t] = kr[(size_t)l * 256 + t];
    li[t] = ki[(size_t)l * 256 + t];
    __syncthreads();

    if (t < 128) {
        int e = t >> 2, chunk = t & 3;          // e in 0..31
        int ci = e >> 4;                        // 0,1
        int c = 0, d = ci;                      // (0,0),(0,1)
        int m = (e >> 2) & 3, q = e & 3;
        int i1 = m >> 1, j1 = m & 1, i2 = q >> 1, j2 = q & 1;
        int off1 = c * 4 + 2 * i1 + i2;
        int off2 = d * 4 + 2 * j1 + j2;
        float ar = 0.f, ai = 0.f;
        #pragma unroll
        for (int kk = 0; kk < 4; ++kk) {
            int kbase = (chunk * 4 + kk) * 16;
            #pragma unroll
            for (int a = 0; a < 2; ++a) {
                int x1 = kbase + a * 8 + off1;
                int x2 = kbase + a * 8 + off2;
                float k1r = lr[x1], k1i = li[x1];
                float k2r = lr[x2], k2i = li[x2];
                ar += k1r * k2r + k1i * k2i;    // K1 * conj(K2)
                ai += k1i * k2r - k1r * k2i;
            }
        }
        ar += __shfl_xor(ar, 1); ar += __shfl_xor(ar, 2);
        ai += __shfl_xor(ai, 1); ai += __shfl_xor(ai, 2);
        if (chunk == 0) { gr[e] = ar; gi[e] = ai; }
    }
    __syncthreads();

    if (t < 12) {
        int r3 = t >> 2, col = t & 3;
        int row = (r3 == 0) ? 0 : r3 + 1;       // 0,2,3
        int ci = (row == 0) ? 0 : 1;
        int base = ci * 16;
        float Ur[4], Ui[4];
        #pragma unroll
        for (int q = 0; q < 4; ++q) {
            if (col == 0)      { Ur[q] = gr[base + q];      Ui[q] = gi[base + q]; }
            else if (col == 1) { Ur[q] = gr[base + 12 + q]; Ui[q] = gi[base + 12 + q]; }
            else {
                float t1r = gr[base + 4 + q], t1i = gi[base + 4 + q];
                float t2r = gr[base + 8 + q], t2i = gi[base + 8 + q];
                if (col == 2) { Ur[q] = t1r + t2r;    Ui[q] = t1i + t2i; }
                else          { Ur[q] = -(t1i - t2i); Ui[q] = t1r - t2r; }   // i*(T1-T2)
            }
        }
        float A, Bc, Cc;
        if (row == 3) { A = Ui[0]; Bc = Ui[1] + Ui[2]; Cc = Ui[3]; }
        else          { A = Ur[0]; Bc = Ur[1] + Ur[2]; Cc = Ur[3]; }
        o[t]      = Cc;
        o[12 + t] = A - Cc;
        o[24 + t] = Bc;
    }
}

// ---------------------------------------------------------------------------
// Kernel 2: per (batch-chunk, segment) product of SEGF transfer matrices.
// All wide ops: staging 7x dwordx4 loads + 7x b128 LDS writes; consume 7x
// b128 LDS reads (1 per layer-pair); P out as 3x dwordx4. Tc via scalar
// s_load (wave-uniform). pA/pB hold rows {0,2,3}; implicit row1.
// ---------------------------------------------------------------------------
__global__ void __launch_bounds__(256, 4)
seg_fused(const float* __restrict__ X, const float* __restrict__ Tc,
          float* __restrict__ P) {
    __shared__ float4 xxs4[256 * 7];            // 28672 B; [row*7 + pair]
    int t  = threadIdx.x;
    int s  = blockIdx.y;
    int ls = s * SEGF;
    int b0 = blockIdx.x * 256;
    const float* tl0 = Tc + (size_t)ls * TCW;   // wave-uniform -> s_load
    const float2* Xp = (const float2*)X;

    // stage: pair p covers sites (ls+1+2p, ls+2+2p); pair start is odd so
    // only the final pair of the last segment can touch site 784 -> clamp
    // start to 782 and take .zw for the real site (pad layer xx don't-care).
    #pragma unroll
    for (int e = 0; e < 7; ++e) {
        int idx  = t + e * 256;                 // 0..1791
        int row  = idx / 7;
        int p    = idx - row * 7;
        int s0   = ls + 1 + 2 * p;
        bool cl  = (s0 > N_SITES - 2);          // only s=55, p=6
        int  s0c = cl ? (N_SITES - 2) : s0;
        float4 f = *(const float4*)(Xp + (size_t)(b0 + row) * N_SITES + s0c);
        float ax = cl ? f.z : f.x;
        float ay = cl ? f.w : f.y;
        float inva = __builtin_amdgcn_rcpf(fmaf(ax, ax, ay * ay));
        float invb = __builtin_amdgcn_rcpf(fmaf(f.z, f.z, f.w * f.w));
        xxs4[row * 7 + p] = make_float4(ax * ax * inva, ax * ay * inva,
                                        f.z * f.z * invb, f.z * f.w * invb);
    }
    __syncthreads();

    float pA[12], pB[12];
    #pragma unroll
    for (int i = 0; i < 12; ++i) pA[i] = 0.f;
    pA[0] = 1.f; pA[6] = 1.f; pA[11] = 1.f;     // identity rows {0,2,3}

#define STEPX(SRC, DST, I, XX0, XX1)                                            \
    {                                                                           \
        const float* tl = tl0 + (I) * TCW;      /* uniform -> s_load */         \
        float R[12];                                                            \
        _Pragma("unroll")                                                       \
        for (int e = 0; e < 12; ++e)                                            \
            R[e] = fmaf(tl[24 + e], (XX1), fmaf(tl[12 + e], (XX0), tl[e]));     \
        _Pragma("unroll")                                                       \
        for (int r = 0; r < 3; ++r) {                                           \
            float Rd = R[r * 4 + 0] - R[r * 4 + 1];                             \
            float R1 = R[r * 4 + 1];                                            \
            _Pragma("unroll")                                                   \
            for (int cc = 0; cc < 4; ++cc) {                                    \
                float base = (cc < 2) ? R1 : 0.f;                               \
                DST[r * 4 + cc] =                                               \
                    fmaf(Rd, SRC[cc],                                           \
                    fmaf(R[r * 4 + 2], SRC[4 + cc],                             \
                    fmaf(R[r * 4 + 3], SRC[8 + cc], base)));                    \
            }                                                                   \
        }                                                                       \
    }

    #pragma unroll
    for (int p = 0; p < 7; ++p) {               // 2 layers per LDS read
        float4 xp4 = xxs4[t * 7 + p];
        STEPX(pA, pB, 2 * p,     xp4.x, xp4.y);
        STEPX(pB, pA, 2 * p + 1, xp4.z, xp4.w);
    }
#undef STEPX

    int b = b0 + t;
    float4* P4 = (float4*)P;
    #pragma unroll
    for (int k = 0; k < 3; ++k)
        P4[((size_t)(s * 3 + k)) * B_BATCH + b] =
            make_float4(pA[4 * k], pA[4 * k + 1], pA[4 * k + 2], pA[4 * k + 3]);
}

// ---------------------------------------------------------------------------
// Kernel 3: two-level combine (8 groups x 7-chain, then 8-chain).
// Row 1 reconstructed via trace conservation.
// ---------------------------------------------------------------------------
__global__ void __launch_bounds__(256)
combine56(const float* __restrict__ X, const float* __restrict__ P,
          float* __restrict__ out) {
    __shared__ float q[256][13];
    int t = threadIdx.x;
    int j = t >> 5, bl = t & 31;
    int b = blockIdx.x * 32 + bl;
    const float4* P4 = (const float4*)P;

    float qa[12], qb[12];
    #pragma unroll
    for (int i = 0; i < 12; ++i) qa[i] = 0.f;
    qa[0] = 1.f; qa[6] = 1.f; qa[11] = 1.f;

#define CSTEP(SRC, DST, K)                                                      \
    {                                                                           \
        float m[12];                                                            \
        _Pragma("unroll")                                                       \
        for (int k = 0; k < 3; ++k) {                                           \
            float4 mv = P4[((size_t)((j * 7 + (K)) * 3 + k)) * B_BATCH + b];    \
            m[4 * k + 0] = mv.x; m[4 * k + 1] = mv.y;                           \
            m[4 * k + 2] = mv.z; m[4 * k + 3] = mv.w;                           \
        }                                                                       \
        _Pragma("unroll")                                                       \
        for (int r = 0; r < 3; ++r) {                                           \
            float Rd = m[r * 4 + 0] - m[r * 4 + 1];                             \
            float R1 = m[r * 4 + 1];                                            \
            _Pragma("unroll")                                                   \
            for (int cc = 0; cc < 4; ++cc) {                                    \
                float base = (cc < 2) ? R1 : 0.f;                               \
                DST[r * 4 + cc] =                                               \
                    fmaf(Rd, SRC[cc],                                           \
                    fmaf(m[r * 4 + 2], SRC[4 + cc],                             \
                    fmaf(m[r * 4 + 3], SRC[8 + cc], base)));                    \
            }                                                                   \
        }                                                                       \
    }
    CSTEP(qa, qb, 0); CSTEP(qb, qa, 1);
    CSTEP(qa, qb, 2); CSTEP(qb, qa, 3);
    CSTEP(qa, qb, 4); CSTEP(qb, qa, 5);
    CSTEP(qa, qb, 6);                          // result in qb
#undef CSTEP

    #pragma unroll
    for (int i = 0; i < 12; ++i) q[t][i] = qb[i];
    __syncthreads();

    if (t < 32) {
        int b2 = blockIdx.x * 32 + t;
        const float2* Xp = (const float2*)X;
        float2 xv = Xp[(size_t)b2 * N_SITES];
        float inv = __builtin_amdgcn_rcpf(fmaf(xv.x, xv.x, xv.y * xv.y));
        float v0 = xv.x * xv.x * inv;          // s00
        float v1 = xv.y * xv.y * inv;          // s11
        float v2 = xv.x * xv.y * inv;          // u
        float v3 = 0.f;                        // w
        #pragma unroll
        for (int jj = 0; jj < 8; ++jj) {
            const float* qq = q[jj * 32 + t];
            float n0 = fmaf(qq[0], v0, fmaf(qq[1], v1, fmaf(qq[2],  v2, qq[3]  * v3)));
            float n2 = fmaf(qq[4], v0, fmaf(qq[5], v1, fmaf(qq[6],  v2, qq[7]  * v3)));
            float n3 = fmaf(qq[8], v0, fmaf(qq[9], v1, fmaf(qq[10], v2, qq[11] * v3)));
            float n1 = (v0 + v1) - n0;         // trace conservation
            v0 = n0; v1 = n1; v2 = n2; v3 = n3;
        }
        out[b2] = v0;
    }
}

// ---------------------------------------------------------------------------
extern "C" void kernel_launch(void* const* d_in, const int* in_sizes, int n_in,
                              void* d_out, int out_size, void* d_ws, size_t ws_size,
                              hipStream_t stream) {
    const float* X  = (const float*)d_in[0];
    const float* kr = (const float*)d_in[1];
    const float* ki = (const float*)d_in[2];
    float* out = (float*)d_out;

    float* Tc = (float*)d_ws;
    const size_t Tb = ((size_t)L_PAD * TCW * sizeof(float) + 255) & ~(size_t)255;
    float* P = (float*)((char*)d_ws + Tb);      // 56*12*8192*4 = 22.0 MB

    build_T<<<L_PAD, 256, 0, stream>>>(kr, ki, Tc);

    dim3 gs(B_BATCH / 256, GF);
    seg_fused<<<gs, 256, 0, stream>>>(X, Tc, P);

    combine56<<<B_BATCH / 32, 256, 0, stream>>>(X, P, out);
}